// Round 1
// baseline (147.140 us; speedup 1.0000x reference)
//
#include <hip/hip_runtime.h>

#define N_Q 100000
#define N_M 5000
#define BLK 256

__global__ __launch_bounds__(BLK) void nn1_kernel(
    const float* __restrict__ q,
    const float* __restrict__ maze,
    const float* __restrict__ ts,
    float* __restrict__ out)
{
    __shared__ float2 smaze[N_M];
    const float2* mz = (const float2*)maze;
    for (int i = threadIdx.x; i < N_M; i += BLK) smaze[i] = mz[i];
    __syncthreads();

    const int qi = blockIdx.x * BLK + threadIdx.x;
    if (qi >= N_Q) return;

    const float2 xq = ((const float2*)q)[qi];
    const float x0 = xq.x, x1 = xq.y;

    float best = 3.4e38f;
    int bidx = 0;
    #pragma unroll 8
    for (int m = 0; m < N_M; ++m) {
        float2 p = smaze[m];
        // Exact numpy fp32 arithmetic: sub, square, square, add — no FMA
        // contraction (a contracted fma changes rounding and can flip the
        // argmin on near-ties; ts_proj[best] is uncorrelated across indices
        // so one flip blows the absmax threshold).
        float dx = __fsub_rn(x0, p.x);
        float dy = __fsub_rn(x1, p.y);
        float d2 = __fadd_rn(__fmul_rn(dx, dx), __fmul_rn(dy, dy));
        if (d2 < best) { best = d2; bidx = m; }  // strict < == argmin first-occurrence
    }

    const float2 bp = mz[bidx];
    out[2 * qi]     = bp.x;
    out[2 * qi + 1] = bp.y;
    out[2 * N_Q + qi] = ts[bidx];
}

extern "C" void kernel_launch(void* const* d_in, const int* in_sizes, int n_in,
                              void* d_out, int out_size, void* d_ws, size_t ws_size,
                              hipStream_t stream) {
    const float* q    = (const float*)d_in[0];  // euclidean_data [N,2]
    const float* maze = (const float*)d_in[1];  // maze_points   [M,2]
    const float* ts   = (const float*)d_in[2];  // ts_proj       [M]
    float* out = (float*)d_out;                 // [N*2] proj_pos ++ [N] linear_pos

    const int grid = (N_Q + BLK - 1) / BLK;
    nn1_kernel<<<grid, BLK, 0, stream>>>(q, maze, ts, out);
}

// Round 2
// 109.496 us; speedup vs baseline: 1.3438x; 1.3438x over previous
//
#include <hip/hip_runtime.h>

#define N_Q 100000
#define N_M 5000
#define CH 4            // lanes (M-chunks) per query
#define CHUNK 1250      // N_M / CH
#define BLK 256
#define QPB (BLK / CH)  // 64 queries per block

__global__ __launch_bounds__(BLK) void nn1_kernel(
    const float* __restrict__ q,
    const float* __restrict__ maze,
    const float* __restrict__ ts,
    float* __restrict__ out)
{
    __shared__ float2 smaze[N_M];
    const float2* mz = (const float2*)maze;
    for (int i = threadIdx.x; i < N_M; i += BLK) smaze[i] = mz[i];
    __syncthreads();

    const int t  = threadIdx.x;
    const int qi = blockIdx.x * QPB + (t >> 2);
    const int c  = t & 3;                  // which M-chunk this lane scans
    if (qi >= N_Q) return;                 // after syncthreads: safe

    const float2 xq = ((const float2*)q)[qi];
    const float x0 = xq.x, x1 = xq.y;

    float best = 3.4e38f;
    int bidx = 0;
    const int m0 = c * CHUNK;
    // 2 points per ds_read_b128; chunk bases are 4 banks apart -> conflict-free
    #pragma unroll 5
    for (int k = 0; k < CHUNK; k += 2) {
        float4 pp = ((const float4*)smaze)[(m0 + k) >> 1];
        // Exact numpy fp32 arithmetic: sub, mul, mul, add — no FMA contraction
        // (contraction changes rounding and can flip argmin on near-ties).
        float dx0 = __fsub_rn(x0, pp.x);
        float dy0 = __fsub_rn(x1, pp.y);
        float d20 = __fadd_rn(__fmul_rn(dx0, dx0), __fmul_rn(dy0, dy0));
        if (d20 < best) { best = d20; bidx = m0 + k; }
        float dx1 = __fsub_rn(x0, pp.z);
        float dy1 = __fsub_rn(x1, pp.w);
        float d21 = __fadd_rn(__fmul_rn(dx1, dx1), __fmul_rn(dy1, dy1));
        if (d21 < best) { best = d21; bidx = m0 + k + 1; }
    }

    // Combine the 4 chunk-lanes: lexicographic (d2, idx) min == global
    // first-occurrence argmin (lower chunk => lower idx).
    #pragma unroll
    for (int s = 1; s < CH; s <<= 1) {
        float ob = __shfl_xor(best, s);
        int   oi = __shfl_xor(bidx, s);
        if (ob < best || (ob == best && oi < bidx)) { best = ob; bidx = oi; }
    }

    if (c == 0) {
        const float2 bp = mz[bidx];
        out[2 * qi]       = bp.x;
        out[2 * qi + 1]   = bp.y;
        out[2 * N_Q + qi] = ts[bidx];
    }
}

extern "C" void kernel_launch(void* const* d_in, const int* in_sizes, int n_in,
                              void* d_out, int out_size, void* d_ws, size_t ws_size,
                              hipStream_t stream) {
    const float* q    = (const float*)d_in[0];  // euclidean_data [N,2]
    const float* maze = (const float*)d_in[1];  // maze_points   [M,2]
    const float* ts   = (const float*)d_in[2];  // ts_proj       [M]
    float* out = (float*)d_out;                 // [N*2] proj_pos ++ [N] linear_pos

    const int grid = (N_Q + QPB - 1) / QPB;     // 1563
    nn1_kernel<<<grid, BLK, 0, stream>>>(q, maze, ts, out);
}